// Round 9
// baseline (105.350 us; speedup 1.0000x reference)
//
#include <hip/hip_runtime.h>
#include <stdint.h>

// Segmented kNN graph: M=65536 pts, D=16, 64 segments x 1024 pts, K=16.
// Output: int32 src[M*16] then int32 dst[M*16].
//
// v18 = v17 + stage/compute SOFTWARE PIPELINE. v17 decomposition:
// dur = fill(41) + fixed overhead(~14) + kernel(~20); kernel = VALU ~10us
// (selection backbone near-minimal), LDS pipe ~5us (BW-bound), MFMA 0.6us.
// Last clean structural waste: staging was a fully serial prefix, yet
// staging chunk i is exactly the data batch i consumes. v18 processes
// chunks in order j0^k (j0 = the block's query chunk, staged first so
// bfrag is ready after one barrier). Steady state: issue chunk k+1 global
// loads (L2-hit ~200-300cyc) -> batch k (16 MFMA tiles + keys, hides the
// load) -> convert/LDS-write chunk k+1 -> barrier. Keys carry absolute
// quad ids so the merge tree is order-invariant -> bit-identical output.
//
// Carried from v17: flattened selection (4 independent batches P0..P3,
// 4 sort16, balanced keep16 tree; crit path 7->3 stages). From v16:
// XOR-swizzled sc (cand's dim-quad d at slot d ^ ((cand>>2)&3)) ->
// conflict-free LDS, swizzle folds into base pointers. From v12: quad-id
// keys (f32 quad-min via min3+min, 8-bit qid); repair via 4 MFMA tiles
// over all 64 winner-members (wave-uniform row select, contiguous ssq
// b128 C-operand); top-16 of R alone is exact. 1024-thr blocks, 256
// q/block, grid 256, __launch_bounds__(1024,1); norms via 4-lane shfl
// reduce; query f16 recovered from -2c tile by exact *(-0.5).
// Keys: quad = f32bits&~0xFF | qid(8b); member = f32bits&~0x3FF | idx(10b).
// MFMA 16x16x16f16, C operand carries |c|^2+128.

#define L_SEG 1024
#define M_PTS 65536

typedef __fp16 fp16x2 __attribute__((ext_vector_type(2)));
typedef __fp16 fp16x4 __attribute__((ext_vector_type(4)));
typedef float  f32x4  __attribute__((ext_vector_type(4)));

__device__ __forceinline__ uint32_t umn(uint32_t a, uint32_t b) { return a < b ? a : b; }
__device__ __forceinline__ uint32_t umx(uint32_t a, uint32_t b) { return a > b ? a : b; }

#define CE(arr, i, p) { uint32_t lo = umn(arr[i], arr[p]); uint32_t hi = umx(arr[i], arr[p]); arr[i] = lo; arr[p] = hi; }

// bitonic clean of 16 (input bitonic, output sorted ascending): 32 CEs
__device__ __forceinline__ void clean16(uint32_t* A) {
    #pragma unroll
    for (int j = 8; j > 0; j >>= 1) {
        #pragma unroll
        for (int i = 0; i < 16; ++i) {
            int p = i ^ j;
            if (p > i) CE(A, i, p);
        }
    }
}

// Batcher odd-even mergesort-16, ascending (63 CEs)
__device__ __forceinline__ void sort16(uint32_t* B) {
    #pragma unroll
    for (int p = 1; p < 16; p <<= 1) {
        #pragma unroll
        for (int k = p; k >= 1; k >>= 1) {
            #pragma unroll
            for (int j = (k & (p - 1)); j + k < 16; j += 2 * k) {
                #pragma unroll
                for (int i = 0; i <= ((k - 1 < 15 - j - k) ? k - 1 : 15 - j - k); ++i) {
                    if ((i + j) / (2 * p) == (i + j + k) / (2 * p)) CE(B, i + j, i + j + k);
                }
            }
        }
    }
}

// merge sorted S (descending-taken) into sorted A, keep lowest 16
__device__ __forceinline__ void keep16(uint32_t* A, const uint32_t* S) {
    #pragma unroll
    for (int i = 0; i < 16; ++i) A[i] = umn(A[i], S[15 - i]);
    clean16(A);
}

// cross-lane merges over g (xor 16 then 32): disjoint contents per lane
__device__ __forceinline__ void mergeg(uint32_t* A) {
    #pragma unroll
    for (int m = 16; m <= 32; m <<= 1) {
        uint32_t P[16];
        #pragma unroll
        for (int i = 0; i < 16; ++i) P[i] = (uint32_t)__shfl_xor((int)A[15 - i], m, 64);
        #pragma unroll
        for (int i = 0; i < 16; ++i) A[i] = umn(A[i], P[i]);
        clean16(A);
    }
}

__device__ __forceinline__ uint32_t sel4(const uint32_t* A, int g, int v) {
    uint32_t t01 = (g & 1) ? A[4 + v]  : A[v];
    uint32_t t23 = (g & 1) ? A[12 + v] : A[8 + v];
    return (g & 2) ? t23 : t01;
}

// one 256-cand batch: 16 MFMA tiles -> 16 packed quad-min keys (unsorted)
__device__ __forceinline__ void batch16(const __fp16* ap, const float* sqp,
                                        fp16x4 bfrag, int it, int g, uint32_t* P) {
    #pragma unroll
    for (int t = 0; t < 16; ++t) {
        const int cb = it * 256 + t * 16;
        fp16x4 af = *(const fp16x4*)(ap + (size_t)cb * 16);
        f32x4  sq = *(const f32x4*)(sqp + cb);
        f32x4 acc = __builtin_amdgcn_mfma_f32_16x16x16f16(af, bfrag, sq, 0, 0, 0);
        float m = fminf(fminf(fminf(acc[0], acc[1]), acc[2]), acc[3]);
        P[t] = (__float_as_uint(m) & 0xFFFFFF00u) | (uint32_t)(it * 64 + t * 4) | (uint32_t)g;
    }
}

// convert + LDS-write one staged chunk (v already loaded), incl. norms
__device__ __forceinline__ void stage_store(__fp16* sc, float* ssq, int widx,
                                            int tid, int j, f32x4 v) {
    fp16x4* scv = (fp16x4*)sc;
    union { fp16x2 h2[2]; fp16x4 h4; } u;
    u.h2[0] = __builtin_amdgcn_cvt_pkrtz(-2.0f * v[0], -2.0f * v[1]);
    u.h2[1] = __builtin_amdgcn_cvt_pkrtz(-2.0f * v[2], -2.0f * v[3]);
    scv[widx + 1024 * j] = u.h4;
    // lanes t, t^1, t^2, t^3 hold the 4 dim-quads of cand (t>>2)+256j
    float p = v[0] * v[0];
    p = __builtin_fmaf(v[1], v[1], p);
    p = __builtin_fmaf(v[2], v[2], p);
    p = __builtin_fmaf(v[3], v[3], p);
    p += __shfl_xor(p, 1, 64);
    p += __shfl_xor(p, 2, 64);
    if ((tid & 3) == 0) ssq[(tid >> 2) + 256 * j] = p + 128.0f;
}

__global__ __launch_bounds__(1024, 1) void knn_v18_kernel(const float* __restrict__ x,
                                                          int* __restrict__ out) {
    // sc layout: cand's dim-quad d stored at fp16x4 slot cand*4 + (d ^ ((cand>>2)&3))
    __shared__ __attribute__((aligned(16))) __fp16 sc[L_SEG * 16];  // -2*c, swizzled, 32KB
    __shared__ __attribute__((aligned(16))) float  ssq[L_SEG];      // |c|^2 + 128 (f32), 4KB

    const int tid  = threadIdx.x;
    const int b    = blockIdx.x;
    const int seg  = b >> 2;          // 4 blocks per segment
    const int j0   = b & 3;           // the block's query chunk (staged first)
    const int qgrp = j0 << 8;         // 256 queries per block
    const float* xseg = x + (size_t)seg * (L_SEG * 16);
    const f32x4* gx4  = (const f32x4*)xseg;

    // thread tid handles dim-quad (tid&3) of cand (tid>>2)+256j;
    // (cand>>2)&3 = (tid>>4)&3 (j-invariant since 256j>>2 = 64j = 0 mod 4)
    const int widx = (tid & ~3) + ((tid & 3) ^ ((tid >> 4) & 3));

    // ---- prologue: stage the query chunk j0 ----
    stage_store(sc, ssq, widx, tid, j0, gx4[tid + 1024 * j0]);
    __syncthreads();

    const int lane = tid & 63;
    const int w    = tid >> 6;        // wave 0..15
    const int g    = lane >> 4;       // lane owns quad (tilequad + g)
    const int col  = lane & 15;       // query column
    const int qrow = qgrp + w * 16 + col;   // query local index in segment
    const int gsw  = g ^ ((col >> 2) & 3);  // swizzled slot for this lane's k-quad

    const fp16x4 mh = {(__fp16)-0.5f, (__fp16)-0.5f, (__fp16)-0.5f, (__fp16)-0.5f};
    // B fragment: rtz(q) recovered exactly from staged rtz(-2q) via *(-0.5).
    // qrow's swizzle = g ^ ((qrow>>2)&3) = gsw (qgrp,w*16 are 0 mod 4 after >>2).
    fp16x4 bfrag;
    {
        fp16x4 raw = *(const fp16x4*)(sc + (size_t)qrow * 16 + gsw * 4);
        bfrag = raw * mh;
    }

    // af base: cand cb+col, k-quad g -> slot g ^ (((cb+col)>>2)&3) = gsw
    // (cb is a multiple of 16). Loop-invariant -> fold into ap.
    const __fp16* ap  = sc + (size_t)col * 16 + gsw * 4;   // + cand*16 halves
    const float*  sqp = ssq + g * 4;

    // ---- pipelined: batch(j0^k) overlaps chunk (j0^(k+1)) staging ----
    uint32_t P0[16], P1[16], P2[16], P3[16];
    {
        f32x4 vn = gx4[tid + 1024 * (j0 ^ 1)];   // issue load chunk j0^1
        batch16(ap, sqp, bfrag, j0, g, P0);      // compute on chunk j0
        stage_store(sc, ssq, widx, tid, j0 ^ 1, vn);
        __syncthreads();
    }
    {
        f32x4 vn = gx4[tid + 1024 * (j0 ^ 2)];
        batch16(ap, sqp, bfrag, j0 ^ 1, g, P1);
        stage_store(sc, ssq, widx, tid, j0 ^ 2, vn);
        __syncthreads();
    }
    {
        f32x4 vn = gx4[tid + 1024 * (j0 ^ 3)];
        batch16(ap, sqp, bfrag, j0 ^ 2, g, P2);
        stage_store(sc, ssq, widx, tid, j0 ^ 3, vn);
        __syncthreads();
    }
    batch16(ap, sqp, bfrag, j0 ^ 3, g, P3);

    // ---- 4 independent sorts -> balanced merge tree (order-invariant) ----
    sort16(P0);
    sort16(P1);
    sort16(P2);
    sort16(P3);
    keep16(P0, P1);   // top-16 of chunks j0, j0^1
    keep16(P2, P3);   // top-16 of chunks j0^2, j0^3
    keep16(P0, P2);   // per-lane top-16 of all 64 quad keys
    uint32_t* A = P0;

    mergeg(A);  // all lanes now hold the IDENTICAL sorted top-16 quad keys

    // ---- repair via MFMA: distances of all 64 winner-members x 16 queries ----
    uint32_t R[16];
    {
        const uint32_t c2a = (uint32_t)(col & 4);   // (col>>2)&1
        const uint32_t c2b = (uint32_t)(col & 8);   // (col>>2)&2
        const uint32_t v0  = (uint32_t)(col & 3);
        #pragma unroll
        for (int j = 0; j < 4; ++j) {
            // A-operand: row = col -> member index from A[4j + (col>>2)]
            const uint32_t t01 = c2a ? A[4*j + 1] : A[4*j + 0];
            const uint32_t t23 = c2a ? A[4*j + 3] : A[4*j + 2];
            const uint32_t awc = c2b ? t23 : t01;
            const uint32_t qid = awc & 255u;
            const uint32_t mrow = (qid << 2) | v0;
            // swizzled slot for k-quad g of cand mrow: g ^ ((mrow>>2)&3) = g ^ (qid&3)
            const uint32_t msw = ((uint32_t)g ^ (qid & 3u)) << 2;
            fp16x4 af = *(const fp16x4*)(sc + (size_t)mrow * 16 + msw);
            // C-operand + key base: rows 4g..4g+3 -> quad A[4j + g]
            const uint32_t u01 = (g & 1) ? A[4*j + 1] : A[4*j + 0];
            const uint32_t u23 = (g & 1) ? A[4*j + 3] : A[4*j + 2];
            const uint32_t awg = (g & 2) ? u23 : u01;
            const uint32_t ib  = (awg & 255u) << 2;          // first member cand
            f32x4 sq = *(const f32x4*)(ssq + (size_t)ib);    // contiguous b128
            f32x4 acc = __builtin_amdgcn_mfma_f32_16x16x16f16(af, bfrag, sq, 0, 0, 0);
            R[j*4 + 0] = (__float_as_uint(acc[0]) & 0xFFFFFC00u) | ib;
            R[j*4 + 1] = (__float_as_uint(acc[1]) & 0xFFFFFC00u) | (ib + 1u);
            R[j*4 + 2] = (__float_as_uint(acc[2]) & 0xFFFFFC00u) | (ib + 2u);
            R[j*4 + 3] = (__float_as_uint(acc[3]) & 0xFFFFFC00u) | (ib + 3u);
        }
    }
    sort16(R);
    mergeg(R);  // 64 member-distances across g-lanes -> exact final top-16

    // ---- epilogue: lane (g,col) writes int4 #g of src and dst for its query ----
    const int base = seg * L_SEG;
    const int q    = base + qrow;
    int4 sv;
    sv.x = base + (int)(sel4(R, g, 0) & 1023u);
    sv.y = base + (int)(sel4(R, g, 1) & 1023u);
    sv.z = base + (int)(sel4(R, g, 2) & 1023u);
    sv.w = base + (int)(sel4(R, g, 3) & 1023u);
    ((int4*)out)[(size_t)q * 4 + g] = sv;
    ((int4*)out)[(size_t)M_PTS * 4 + (size_t)q * 4 + g] = make_int4(q, q, q, q);
}

extern "C" void kernel_launch(void* const* d_in, const int* in_sizes, int n_in,
                              void* d_out, int out_size, void* d_ws, size_t ws_size,
                              hipStream_t stream) {
    const float* x = (const float*)d_in[0];
    // d_in[1] = segs (int64, all 1024) — static per problem setup, unused.
    int* out = (int*)d_out;
    (void)d_ws; (void)ws_size;
    knn_v18_kernel<<<dim3(256), dim3(1024), 0, stream>>>(x, out);
}

// Round 10
// 75.346 us; speedup vs baseline: 1.3982x; 1.3982x over previous
//
#include <hip/hip_runtime.h>
#include <stdint.h>

// Segmented kNN graph: M=65536 pts, D=16, 64 segments x 1024 pts, K=16.
// Output: int32 src[M*16] then int32 dst[M*16].
//
// v19 = v17's flattened selection under a BOUNDED LIVE SET. v18 post-
// mortem: keeping P0..P3 (64 regs) live across staging barriers spilled
// (WRITE_SIZE 105MB vs 8MB output, VALUBusy 0.2%, kernel 55us) and the
// compiler PINS 64 arch-VGPRs at 1024-thr blocks instead of using the
// 128 cap -- ILP must fit in ~60 live values. v17 (4 arrays live, no
// barriers) likely part-spilled too, explaining its +1.5us vs predicted
// +5. v19: serial staging (v16-style, known-good), then
//   batch0 -> sort0 into A;
//   batchK -> sortK -> keep16(A, PK) for K=1..3 (PK dies immediately).
// Peak live ~= A(16)+P(16)+tile internals ~= 45. Batches stay mutually
// independent so the scheduler still overlaps batch K+1 MFMA/LDS with
// keep16 K (v17's ILP); critical path 126+240 ops (vs v17 286 nominal)
// but zero scratch. Bit-identical output (same keys, order-invariant).
//
// Carried from v16: XOR-swizzled sc (cand's dim-quad d at slot
// d ^ ((cand>>2)&3)) -> conflict-free LDS, swizzle folds into base
// pointers. From v12: quad-id keys (f32 quad-min via min3+min, 8-bit
// qid); repair via 4 MFMA tiles over all 64 winner-members (wave-uniform
// row select, contiguous ssq b128 C-operand); top-16 of R alone is
// exact. 1024-thr blocks, 256 q/block, grid 256, __launch_bounds__
// (1024,1); norms via 4-lane shfl reduce; query f16 recovered from -2c
// tile by exact *(-0.5).
// Keys: quad = f32bits&~0xFF | qid(8b); member = f32bits&~0x3FF | idx(10b).
// MFMA 16x16x16f16, C operand carries |c|^2+128.

#define L_SEG 1024
#define M_PTS 65536

typedef __fp16 fp16x2 __attribute__((ext_vector_type(2)));
typedef __fp16 fp16x4 __attribute__((ext_vector_type(4)));
typedef float  f32x4  __attribute__((ext_vector_type(4)));

__device__ __forceinline__ uint32_t umn(uint32_t a, uint32_t b) { return a < b ? a : b; }
__device__ __forceinline__ uint32_t umx(uint32_t a, uint32_t b) { return a > b ? a : b; }

#define CE(arr, i, p) { uint32_t lo = umn(arr[i], arr[p]); uint32_t hi = umx(arr[i], arr[p]); arr[i] = lo; arr[p] = hi; }

// bitonic clean of 16 (input bitonic, output sorted ascending): 32 CEs
__device__ __forceinline__ void clean16(uint32_t* A) {
    #pragma unroll
    for (int j = 8; j > 0; j >>= 1) {
        #pragma unroll
        for (int i = 0; i < 16; ++i) {
            int p = i ^ j;
            if (p > i) CE(A, i, p);
        }
    }
}

// Batcher odd-even mergesort-16, ascending (63 CEs)
__device__ __forceinline__ void sort16(uint32_t* B) {
    #pragma unroll
    for (int p = 1; p < 16; p <<= 1) {
        #pragma unroll
        for (int k = p; k >= 1; k >>= 1) {
            #pragma unroll
            for (int j = (k & (p - 1)); j + k < 16; j += 2 * k) {
                #pragma unroll
                for (int i = 0; i <= ((k - 1 < 15 - j - k) ? k - 1 : 15 - j - k); ++i) {
                    if ((i + j) / (2 * p) == (i + j + k) / (2 * p)) CE(B, i + j, i + j + k);
                }
            }
        }
    }
}

// merge sorted S (descending-taken) into sorted A, keep lowest 16
__device__ __forceinline__ void keep16(uint32_t* A, const uint32_t* S) {
    #pragma unroll
    for (int i = 0; i < 16; ++i) A[i] = umn(A[i], S[15 - i]);
    clean16(A);
}

// cross-lane merges over g (xor 16 then 32): disjoint contents per lane
__device__ __forceinline__ void mergeg(uint32_t* A) {
    #pragma unroll
    for (int m = 16; m <= 32; m <<= 1) {
        uint32_t P[16];
        #pragma unroll
        for (int i = 0; i < 16; ++i) P[i] = (uint32_t)__shfl_xor((int)A[15 - i], m, 64);
        #pragma unroll
        for (int i = 0; i < 16; ++i) A[i] = umn(A[i], P[i]);
        clean16(A);
    }
}

__device__ __forceinline__ uint32_t sel4(const uint32_t* A, int g, int v) {
    uint32_t t01 = (g & 1) ? A[4 + v]  : A[v];
    uint32_t t23 = (g & 1) ? A[12 + v] : A[8 + v];
    return (g & 2) ? t23 : t01;
}

// one 256-cand batch: 16 MFMA tiles -> 16 packed quad-min keys (unsorted)
__device__ __forceinline__ void batch16(const __fp16* ap, const float* sqp,
                                        fp16x4 bfrag, int it, int g, uint32_t* P) {
    #pragma unroll
    for (int t = 0; t < 16; ++t) {
        const int cb = it * 256 + t * 16;
        fp16x4 af = *(const fp16x4*)(ap + (size_t)cb * 16);
        f32x4  sq = *(const f32x4*)(sqp + cb);
        f32x4 acc = __builtin_amdgcn_mfma_f32_16x16x16f16(af, bfrag, sq, 0, 0, 0);
        float m = fminf(fminf(fminf(acc[0], acc[1]), acc[2]), acc[3]);
        P[t] = (__float_as_uint(m) & 0xFFFFFF00u) | (uint32_t)(it * 64 + t * 4) | (uint32_t)g;
    }
}

__global__ __launch_bounds__(1024, 1) void knn_v19_kernel(const float* __restrict__ x,
                                                          int* __restrict__ out) {
    // sc layout: cand's dim-quad d stored at fp16x4 slot cand*4 + (d ^ ((cand>>2)&3))
    __shared__ __attribute__((aligned(16))) __fp16 sc[L_SEG * 16];  // -2*c, swizzled, 32KB
    __shared__ __attribute__((aligned(16))) float  ssq[L_SEG];      // |c|^2 + 128 (f32), 4KB

    const int tid  = threadIdx.x;
    const int b    = blockIdx.x;
    const int seg  = b >> 2;          // 4 blocks per segment
    const int qgrp = (b & 3) << 8;    // 256 queries per block
    const float* xseg = x + (size_t)seg * (L_SEG * 16);
    const f32x4* gx4  = (const f32x4*)xseg;

    // ---- stage coords * -2 as f16 (swizzled slot); norms via 4-lane shfl reduce ----
    {
        fp16x4* scv = (fp16x4*)sc;
        // thread tid handles dim-quad (tid&3) of cand (tid>>2)+256i;
        // (cand>>2)&3 = (tid>>4)&3 (i-invariant since 64i = 0 mod 4)
        const int widx = (tid & ~3) + ((tid & 3) ^ ((tid >> 4) & 3));
        #pragma unroll
        for (int i = 0; i < 4; ++i) {
            f32x4 v = gx4[tid + 1024 * i];            // coalesced: 16B/lane contiguous
            union { fp16x2 h2[2]; fp16x4 h4; } u;
            u.h2[0] = __builtin_amdgcn_cvt_pkrtz(-2.0f * v[0], -2.0f * v[1]);
            u.h2[1] = __builtin_amdgcn_cvt_pkrtz(-2.0f * v[2], -2.0f * v[3]);
            scv[widx + 1024 * i] = u.h4;
            // lanes t, t^1, t^2, t^3 hold the 4 dim-quads of cand (t>>2)+256i
            float p = v[0] * v[0];
            p = __builtin_fmaf(v[1], v[1], p);
            p = __builtin_fmaf(v[2], v[2], p);
            p = __builtin_fmaf(v[3], v[3], p);
            p += __shfl_xor(p, 1, 64);
            p += __shfl_xor(p, 2, 64);
            if ((tid & 3) == 0) ssq[(tid >> 2) + 256 * i] = p + 128.0f;
        }
    }
    __syncthreads();

    const int lane = tid & 63;
    const int w    = tid >> 6;        // wave 0..15
    const int g    = lane >> 4;       // lane owns quad (tilequad + g)
    const int col  = lane & 15;       // query column
    const int qrow = qgrp + w * 16 + col;   // query local index in segment
    const int gsw  = g ^ ((col >> 2) & 3);  // swizzled slot for this lane's k-quad

    const fp16x4 mh = {(__fp16)-0.5f, (__fp16)-0.5f, (__fp16)-0.5f, (__fp16)-0.5f};
    // B fragment: rtz(q) recovered exactly from staged rtz(-2q) via *(-0.5).
    // qrow's swizzle = g ^ ((qrow>>2)&3) = gsw (qgrp,w*16 are 0 mod 4 after >>2).
    fp16x4 bfrag;
    {
        fp16x4 raw = *(const fp16x4*)(sc + (size_t)qrow * 16 + gsw * 4);
        bfrag = raw * mh;
    }

    // af base: cand cb+col, k-quad g -> slot g ^ (((cb+col)>>2)&3) = gsw
    // (cb is a multiple of 16). Loop-invariant -> fold into ap.
    const __fp16* ap  = sc + (size_t)col * 16 + gsw * 4;   // + cand*16 halves
    const float*  sqp = ssq + g * 4;

    // ---- bounded-live flattened selection: A + one P live at a time ----
    uint32_t A[16];
    batch16(ap, sqp, bfrag, 0, g, A);
    sort16(A);
    {
        uint32_t P[16];
        batch16(ap, sqp, bfrag, 1, g, P);
        sort16(P);
        keep16(A, P);      // P dies here
    }
    {
        uint32_t P[16];
        batch16(ap, sqp, bfrag, 2, g, P);
        sort16(P);
        keep16(A, P);
    }
    {
        uint32_t P[16];
        batch16(ap, sqp, bfrag, 3, g, P);
        sort16(P);
        keep16(A, P);      // per-lane top-16 of all 64 quad keys
    }

    mergeg(A);  // all lanes now hold the IDENTICAL sorted top-16 quad keys

    // ---- repair via MFMA: distances of all 64 winner-members x 16 queries ----
    uint32_t R[16];
    {
        const uint32_t c2a = (uint32_t)(col & 4);   // (col>>2)&1
        const uint32_t c2b = (uint32_t)(col & 8);   // (col>>2)&2
        const uint32_t v0  = (uint32_t)(col & 3);
        #pragma unroll
        for (int j = 0; j < 4; ++j) {
            // A-operand: row = col -> member index from A[4j + (col>>2)]
            const uint32_t t01 = c2a ? A[4*j + 1] : A[4*j + 0];
            const uint32_t t23 = c2a ? A[4*j + 3] : A[4*j + 2];
            const uint32_t awc = c2b ? t23 : t01;
            const uint32_t qid = awc & 255u;
            const uint32_t mrow = (qid << 2) | v0;
            // swizzled slot for k-quad g of cand mrow: g ^ ((mrow>>2)&3) = g ^ (qid&3)
            const uint32_t msw = ((uint32_t)g ^ (qid & 3u)) << 2;
            fp16x4 af = *(const fp16x4*)(sc + (size_t)mrow * 16 + msw);
            // C-operand + key base: rows 4g..4g+3 -> quad A[4j + g]
            const uint32_t u01 = (g & 1) ? A[4*j + 1] : A[4*j + 0];
            const uint32_t u23 = (g & 1) ? A[4*j + 3] : A[4*j + 2];
            const uint32_t awg = (g & 2) ? u23 : u01;
            const uint32_t ib  = (awg & 255u) << 2;          // first member cand
            f32x4 sq = *(const f32x4*)(ssq + (size_t)ib);    // contiguous b128
            f32x4 acc = __builtin_amdgcn_mfma_f32_16x16x16f16(af, bfrag, sq, 0, 0, 0);
            R[j*4 + 0] = (__float_as_uint(acc[0]) & 0xFFFFFC00u) | ib;
            R[j*4 + 1] = (__float_as_uint(acc[1]) & 0xFFFFFC00u) | (ib + 1u);
            R[j*4 + 2] = (__float_as_uint(acc[2]) & 0xFFFFFC00u) | (ib + 2u);
            R[j*4 + 3] = (__float_as_uint(acc[3]) & 0xFFFFFC00u) | (ib + 3u);
        }
    }
    sort16(R);
    mergeg(R);  // 64 member-distances across g-lanes -> exact final top-16

    // ---- epilogue: lane (g,col) writes int4 #g of src and dst for its query ----
    const int base = seg * L_SEG;
    const int q    = base + qrow;
    int4 sv;
    sv.x = base + (int)(sel4(R, g, 0) & 1023u);
    sv.y = base + (int)(sel4(R, g, 1) & 1023u);
    sv.z = base + (int)(sel4(R, g, 2) & 1023u);
    sv.w = base + (int)(sel4(R, g, 3) & 1023u);
    ((int4*)out)[(size_t)q * 4 + g] = sv;
    ((int4*)out)[(size_t)M_PTS * 4 + (size_t)q * 4 + g] = make_int4(q, q, q, q);
}

extern "C" void kernel_launch(void* const* d_in, const int* in_sizes, int n_in,
                              void* d_out, int out_size, void* d_ws, size_t ws_size,
                              hipStream_t stream) {
    const float* x = (const float*)d_in[0];
    // d_in[1] = segs (int64, all 1024) — static per problem setup, unused.
    int* out = (int*)d_out;
    (void)d_ws; (void)ws_size;
    knn_v19_kernel<<<dim3(256), dim3(1024), 0, stream>>>(x, out);
}